// Round 1
// baseline (147.813 us; speedup 1.0000x reference)
//
#include <hip/hip_runtime.h>
#include <hip/hip_fp16.h>

// score[e] = relu(h[src[e]]@W1s + h[dst[e]]@W1d + b1) @ W2 + b2
// N_NODES=100000, N_EDGES=1600000, H=64.
// Phase 1 (node_proj): GEMM [N x 64] @ [64 x 128] via bf16 MFMA 16x16x32.
//   NEW: epilogue quantizes each 64-elem row of P (=h@W1s+b1) and Q (=h@W1d)
//   to int8 with a per-row scale amax/127 (stored fp32 in Psc/Qsc, 800 KB
//   total -> L2-resident). Row amax via 4x shfl_xor over the 16-lane q-group
//   that holds the row. Write traffic 25.6 -> 13.6 MB.
// Phase 2 (edge_score): per-edge gather of 64-B int8 rows (was 128-B fp16):
//   halves both compulsory bytes/gather and the random working set
//   (25.6 -> 12.8 MB), so L2 hit rate rises too. Dequant:
//   x = pu*ps + qu*qs - 127*(ps+qs), relu, dot(W2).

#define HF    64
#define PITCH 144   // int8 LDS row pitch (16-aligned; 4*PITCH/4 % 32 = 16 -> 2-way = free)
#define TPB   2     // 64-node tiles per block

typedef __attribute__((ext_vector_type(8))) short bf16x8;
typedef __attribute__((ext_vector_type(4))) float f32x4;

__device__ __forceinline__ short f2bf(float x) {
    unsigned u = __builtin_bit_cast(unsigned, x);
    unsigned r = (u + 0x7fffu + ((u >> 16) & 1u)) >> 16;
    return (short)r;
}

__device__ __forceinline__ unsigned char q8(float v, float inv) {
    // v in [-amax, amax], inv = 127/amax  ->  result in [0, 254]
    return (unsigned char)(int)rintf(fmaf(v, inv, 127.0f));
}

// ---------------- Phase 1: node projection via MFMA + int8 quant ----------
__global__ __launch_bounds__(256) void node_proj_kernel(
    const float* __restrict__ h, const float* __restrict__ W1,
    const float* __restrict__ b1, unsigned char* __restrict__ P8,
    unsigned char* __restrict__ Q8, float* __restrict__ Psc,
    float* __restrict__ Qsc, int n_nodes)
{
    __shared__ unsigned char eb8[64 * PITCH];   // transpose buffer (int8)
    __shared__ float pscl[64];
    __shared__ float qscl[64];

    const int tid  = threadIdx.x;
    const int wave = tid >> 6;               // 0..3: 16-node strip
    const int lane = tid & 63;
    const int q    = lane >> 4;              // quad 0..3
    const int n    = lane & 15;

    // ---- B fragments once per block: B[k][col], k=kb*32+q*8+j, col=t*16+n --
    // t<4 -> P cols (W1 rows 0..63); t>=4 -> Q cols (W1 rows 64..127).
    bf16x8 bfrag[8][2];
    #pragma unroll
    for (int t = 0; t < 8; ++t) {
        const float* wb = W1 + ((t >= 4) ? HF * HF : 0) + (t & 3) * 16 + n;
        #pragma unroll
        for (int kb = 0; kb < 2; ++kb) {
            #pragma unroll
            for (int j = 0; j < 8; ++j)
                bfrag[t][kb][j] = f2bf(wb[(kb * 32 + q * 8 + j) * HF]);
        }
    }
    const float bias_n  = b1[0 * 16 + n];
    const float bias_n1 = b1[1 * 16 + n];
    const float bias_n2 = b1[2 * 16 + n];
    const float bias_n3 = b1[3 * 16 + n];

    for (int it = 0; it < TPB; ++it) {
        const int tile = blockIdx.x * TPB + it;
        const int n0   = tile * 64;
        if (n0 >= n_nodes) break;            // block-uniform
        const int nrow = (n_nodes - n0 < 64) ? (n_nodes - n0) : 64;

        // ---- A fragments direct from global: A[m][k], m=wave*16+n ----
        bf16x8 a0, a1;
        {
            int row = n0 + wave * 16 + n;
            if (row >= n_nodes) row = n_nodes - 1;
            const float* hr = h + (size_t)row * HF + q * 8;
            const float4 u0 = *(const float4*)(hr);
            const float4 u1 = *(const float4*)(hr + 4);
            const float4 v0 = *(const float4*)(hr + 32);
            const float4 v1 = *(const float4*)(hr + 36);
            a0[0] = f2bf(u0.x); a0[1] = f2bf(u0.y); a0[2] = f2bf(u0.z); a0[3] = f2bf(u0.w);
            a0[4] = f2bf(u1.x); a0[5] = f2bf(u1.y); a0[6] = f2bf(u1.z); a0[7] = f2bf(u1.w);
            a1[0] = f2bf(v0.x); a1[1] = f2bf(v0.y); a1[2] = f2bf(v0.z); a1[3] = f2bf(v0.w);
            a1[4] = f2bf(v1.x); a1[5] = f2bf(v1.y); a1[6] = f2bf(v1.z); a1[7] = f2bf(v1.w);
        }

        // ---- MFMA: 8 N-tiles x 2 K-halves ----
        f32x4 acc[8];
        #pragma unroll
        for (int t = 0; t < 8; ++t) {
            acc[t] = (f32x4){0.f, 0.f, 0.f, 0.f};
            acc[t] = __builtin_amdgcn_mfma_f32_16x16x32_bf16(a0, bfrag[t][0], acc[t], 0, 0, 0);
            acc[t] = __builtin_amdgcn_mfma_f32_16x16x32_bf16(a1, bfrag[t][1], acc[t], 0, 0, 0);
        }

        if (it > 0) __syncthreads();         // prev tile's eb8/pscl reads done

        // ---- epilogue: per-row amax -> int8 quant -> LDS ----
        // C/D layout: col = lane&15 (=n), row = q*4 + reg (+ wave*16).
        // A row's 64 cols live on the 16 lanes sharing q (t=0..3 regs each).
        #pragma unroll
        for (int r = 0; r < 4; ++r) {
            const int row = wave * 16 + q * 4 + r;
            const float p0 = acc[0][r] + bias_n;
            const float p1 = acc[1][r] + bias_n1;
            const float p2 = acc[2][r] + bias_n2;
            const float p3 = acc[3][r] + bias_n3;
            const float q0 = acc[4][r], q1 = acc[5][r];
            const float q2 = acc[6][r], q3 = acc[7][r];

            float pa = fmaxf(fmaxf(__builtin_fabsf(p0), __builtin_fabsf(p1)),
                             fmaxf(__builtin_fabsf(p2), __builtin_fabsf(p3)));
            float qa = fmaxf(fmaxf(__builtin_fabsf(q0), __builtin_fabsf(q1)),
                             fmaxf(__builtin_fabsf(q2), __builtin_fabsf(q3)));
            #pragma unroll
            for (int m = 1; m < 16; m <<= 1) {
                pa = fmaxf(pa, __shfl_xor(pa, m, 16));
                qa = fmaxf(qa, __shfl_xor(qa, m, 16));
            }
            pa = fmaxf(pa, 1e-12f);
            qa = fmaxf(qa, 1e-12f);
            const float pinv = 127.0f / pa;
            const float qinv = 127.0f / qa;

            unsigned char* er = eb8 + row * PITCH;
            er[ 0 + n]      = q8(p0, pinv);
            er[16 + n]      = q8(p1, pinv);
            er[32 + n]      = q8(p2, pinv);
            er[48 + n]      = q8(p3, pinv);
            er[64 +  0 + n] = q8(q0, qinv);
            er[64 + 16 + n] = q8(q1, qinv);
            er[64 + 32 + n] = q8(q2, qinv);
            er[64 + 48 + n] = q8(q3, qinv);
            if (n == 0) {
                pscl[row] = pa * (1.0f / 127.0f);
                qscl[row] = qa * (1.0f / 127.0f);
            }
        }
        __syncthreads();

        // ---- coalesced stores: 64-B int8 rows -> P8 / Q8, scales -> Psc/Qsc
        #pragma unroll
        for (int s = 0; s < 2; ++s) {
            const int idx  = tid + s * 256;   // 0..511 uint4s
            const int row  = idx >> 3;
            const int part = idx & 7;         // 0..3 -> P, 4..7 -> Q
            if (row < nrow) {
                const uint4 v = *(const uint4*)&eb8[row * PITCH + part * 16];
                unsigned char* dstp = (part < 4)
                    ? (P8 + (size_t)(n0 + row) * HF + part * 16)
                    : (Q8 + (size_t)(n0 + row) * HF + (part - 4) * 16);
                *(uint4*)dstp = v;
            }
        }
        if (tid < 128) {
            const int rr = tid & 63;
            if (rr < nrow) {
                if (tid < 64) Psc[n0 + rr] = pscl[rr];
                else          Qsc[n0 + rr] = qscl[rr];
            }
        }
    }
}

// ---------------- Phase 2: per-edge score over int8 rows ------------------
__device__ __forceinline__ float dot8q(uint2 pv, uint2 qv, float4 wa, float4 wb,
                                       float ps, float qs) {
    const float C = -127.0f * (ps + qs);
    float acc = 0.f;
    {
        const unsigned u = pv.x, v = qv.x;
        float x;
        x = fmaf((float)(u & 255u),         ps, fmaf((float)(v & 255u),         qs, C));
        acc = fmaf(fmaxf(x, 0.f), wa.x, acc);
        x = fmaf((float)((u >> 8) & 255u),  ps, fmaf((float)((v >> 8) & 255u),  qs, C));
        acc = fmaf(fmaxf(x, 0.f), wa.y, acc);
        x = fmaf((float)((u >> 16) & 255u), ps, fmaf((float)((v >> 16) & 255u), qs, C));
        acc = fmaf(fmaxf(x, 0.f), wa.z, acc);
        x = fmaf((float)(u >> 24),          ps, fmaf((float)(v >> 24),          qs, C));
        acc = fmaf(fmaxf(x, 0.f), wa.w, acc);
    }
    {
        const unsigned u = pv.y, v = qv.y;
        float x;
        x = fmaf((float)(u & 255u),         ps, fmaf((float)(v & 255u),         qs, C));
        acc = fmaf(fmaxf(x, 0.f), wb.x, acc);
        x = fmaf((float)((u >> 8) & 255u),  ps, fmaf((float)((v >> 8) & 255u),  qs, C));
        acc = fmaf(fmaxf(x, 0.f), wb.y, acc);
        x = fmaf((float)((u >> 16) & 255u), ps, fmaf((float)((v >> 16) & 255u), qs, C));
        acc = fmaf(fmaxf(x, 0.f), wb.z, acc);
        x = fmaf((float)(u >> 24),          ps, fmaf((float)(v >> 24),          qs, C));
        acc = fmaf(fmaxf(x, 0.f), wb.w, acc);
    }
    return acc;
}

__device__ __forceinline__ float red8(float v) {
    v += __shfl_xor(v, 4, 8);
    v += __shfl_xor(v, 2, 8);
    v += __shfl_xor(v, 1, 8);
    return v;
}

__global__ __launch_bounds__(256) void edge_score_kernel(
    const unsigned char* __restrict__ P8, const unsigned char* __restrict__ Q8,
    const float* __restrict__ Psc, const float* __restrict__ Qsc,
    const int* __restrict__ src, const int* __restrict__ dst,
    const float* __restrict__ W2, const float* __restrict__ b2,
    float* __restrict__ out, int n_edges)
{
    const int tid   = blockIdx.x * 256 + threadIdx.x;
    const int sub   = threadIdx.x & 7;
    const int group = tid >> 3;
    const int j0    = sub * 8;
    const int e0    = group * 8;
    if (e0 >= n_edges) return;

    const float4 w2a = *(const float4*)(W2 + j0);
    const float4 w2b = *(const float4*)(W2 + j0 + 4);
    const float bias2 = b2[0];

    if (e0 + 8 <= n_edges) {
        const int4 sA = *(const int4*)(src + e0);
        const int4 sB = *(const int4*)(src + e0 + 4);
        const int4 dA = *(const int4*)(dst + e0);
        const int4 dB = *(const int4*)(dst + e0 + 4);

        // lane sub owns edge e0+sub == global tid: coalesced scale gather,
        // broadcast at use via __shfl(.., e, 8). Scale arrays are L2-resident.
        const float ps_own = Psc[src[e0 + sub]];
        const float qs_own = Qsc[dst[e0 + sub]];

        const uint2 p0 = *(const uint2*)(P8 + (size_t)sA.x * HF + j0);
        const uint2 p1 = *(const uint2*)(P8 + (size_t)sA.y * HF + j0);
        const uint2 p2 = *(const uint2*)(P8 + (size_t)sA.z * HF + j0);
        const uint2 p3 = *(const uint2*)(P8 + (size_t)sA.w * HF + j0);
        const uint2 p4 = *(const uint2*)(P8 + (size_t)sB.x * HF + j0);
        const uint2 p5 = *(const uint2*)(P8 + (size_t)sB.y * HF + j0);
        const uint2 p6 = *(const uint2*)(P8 + (size_t)sB.z * HF + j0);
        const uint2 p7 = *(const uint2*)(P8 + (size_t)sB.w * HF + j0);
        const uint2 q0 = *(const uint2*)(Q8 + (size_t)dA.x * HF + j0);
        const uint2 q1 = *(const uint2*)(Q8 + (size_t)dA.y * HF + j0);
        const uint2 q2 = *(const uint2*)(Q8 + (size_t)dA.z * HF + j0);
        const uint2 q3 = *(const uint2*)(Q8 + (size_t)dA.w * HF + j0);
        const uint2 q4 = *(const uint2*)(Q8 + (size_t)dB.x * HF + j0);
        const uint2 q5 = *(const uint2*)(Q8 + (size_t)dB.y * HF + j0);
        const uint2 q6 = *(const uint2*)(Q8 + (size_t)dB.z * HF + j0);
        const uint2 q7 = *(const uint2*)(Q8 + (size_t)dB.w * HF + j0);

        float s0 = red8(dot8q(p0, q0, w2a, w2b, __shfl(ps_own, 0, 8), __shfl(qs_own, 0, 8)));
        float s1 = red8(dot8q(p1, q1, w2a, w2b, __shfl(ps_own, 1, 8), __shfl(qs_own, 1, 8)));
        float s2 = red8(dot8q(p2, q2, w2a, w2b, __shfl(ps_own, 2, 8), __shfl(qs_own, 2, 8)));
        float s3 = red8(dot8q(p3, q3, w2a, w2b, __shfl(ps_own, 3, 8), __shfl(qs_own, 3, 8)));
        float s4 = red8(dot8q(p4, q4, w2a, w2b, __shfl(ps_own, 4, 8), __shfl(qs_own, 4, 8)));
        float s5 = red8(dot8q(p5, q5, w2a, w2b, __shfl(ps_own, 5, 8), __shfl(qs_own, 5, 8)));
        float s6 = red8(dot8q(p6, q6, w2a, w2b, __shfl(ps_own, 6, 8), __shfl(qs_own, 6, 8)));
        float s7 = red8(dot8q(p7, q7, w2a, w2b, __shfl(ps_own, 7, 8), __shfl(qs_own, 7, 8)));

        if (sub == 0) {
            *(float4*)(out + e0)     = make_float4(s0 + bias2, s1 + bias2,
                                                   s2 + bias2, s3 + bias2);
            *(float4*)(out + e0 + 4) = make_float4(s4 + bias2, s5 + bias2,
                                                   s6 + bias2, s7 + bias2);
        }
    } else {
        for (int e = e0; e < n_edges; ++e) {
            const int s = src[e];
            const int d = dst[e];
            const float ps = Psc[s];
            const float qs = Qsc[d];
            const uint2 pv = *(const uint2*)(P8 + (size_t)s * HF + j0);
            const uint2 qv = *(const uint2*)(Q8 + (size_t)d * HF + j0);
            float sc = red8(dot8q(pv, qv, w2a, w2b, ps, qs));
            if (sub == 0) out[e] = sc + bias2;
        }
    }
}

extern "C" void kernel_launch(void* const* d_in, const int* in_sizes, int n_in,
                              void* d_out, int out_size, void* d_ws, size_t ws_size,
                              hipStream_t stream) {
    const float* h   = (const float*)d_in[0];
    const int*   src = (const int*)d_in[1];
    const int*   dst = (const int*)d_in[2];
    const float* W1  = (const float*)d_in[3];
    const float* b1  = (const float*)d_in[4];
    const float* W2  = (const float*)d_in[5];
    const float* b2  = (const float*)d_in[6];
    float* out = (float*)d_out;

    const int n_nodes = in_sizes[0] / HF;
    const int n_edges = in_sizes[1];

    unsigned char* P8 = (unsigned char*)d_ws;
    unsigned char* Q8 = P8 + (size_t)n_nodes * HF;
    float* Psc = (float*)(Q8 + (size_t)n_nodes * HF);
    float* Qsc = Psc + n_nodes;

    const int ntiles   = (n_nodes + 63) / 64;
    const int nblocks1 = (ntiles + TPB - 1) / TPB;       // 2 tiles per block
    node_proj_kernel<<<nblocks1, 256, 0, stream>>>(h, W1, b1, P8, Q8, Psc, Qsc, n_nodes);

    const int ngroups  = (n_edges + 7) / 8;              // 8 edges per 8-lane group
    const int nblocks2 = (ngroups + 31) / 32;            // 32 groups per 256-thr block
    edge_score_kernel<<<nblocks2, 256, 0, stream>>>(P8, Q8, Psc, Qsc, src, dst, W2, b2, out, n_edges);
}

// Round 2
// 147.410 us; speedup vs baseline: 1.0027x; 1.0027x over previous
//
#include <hip/hip_runtime.h>
#include <hip/hip_fp16.h>

// score[e] = relu(h[src[e]]@W1s + h[dst[e]]@W1d + b1) @ W2 + b2
// N_NODES=100000, N_EDGES=1600000, H=64.
// Phase 1 (node_proj): GEMM [N x 64] @ [64 x 128] via bf16 MFMA 16x16x32.
//   Epilogue quantizes each 64-elem row of P (=h@W1s+b1) and Q (=h@W1d)
//   to int8 with per-row scales. NEW: P and Q rows of the same node are
//   INTERLEAVED into one 128-B line R[n] = [P8[n] | Q8[n]], and scales into
//   S[n] = (psc, qsc). L2 lines are 128 B (r1 evidence: int8 halved payload
//   bytes but FETCH only -7% -> misses pull full 128-B lines). Interleaving
//   makes every fetched line fully referenced (~32 refs/line vs 16) and
//   halves the distinct-line footprint (200K -> 100K lines vs 32K-line L2).
// Phase 2 (edge_score): per-edge gather of the P-half of R[src] and Q-half
//   of R[dst] (64 B each, same line layout), dequant + relu + dot(W2).

#define HF      64
#define RSTRIDE 128   // bytes per node row in R (P half | Q half)
#define PITCH   144   // int8 LDS row pitch (16-aligned; 2-way bank alias = free)
#define TPB     2     // 64-node tiles per block

typedef __attribute__((ext_vector_type(8))) short bf16x8;
typedef __attribute__((ext_vector_type(4))) float f32x4;

__device__ __forceinline__ short f2bf(float x) {
    unsigned u = __builtin_bit_cast(unsigned, x);
    unsigned r = (u + 0x7fffu + ((u >> 16) & 1u)) >> 16;
    return (short)r;
}

__device__ __forceinline__ unsigned char q8(float v, float inv) {
    // v in [-amax, amax], inv = 127/amax  ->  result in [0, 254]
    return (unsigned char)(int)rintf(fmaf(v, inv, 127.0f));
}

// ---------------- Phase 1: node projection via MFMA + int8 quant ----------
__global__ __launch_bounds__(256) void node_proj_kernel(
    const float* __restrict__ h, const float* __restrict__ W1,
    const float* __restrict__ b1, unsigned char* __restrict__ R,
    float* __restrict__ S, int n_nodes)
{
    __shared__ unsigned char eb8[64 * PITCH];   // transpose buffer (int8)
    __shared__ float pscl[64];
    __shared__ float qscl[64];

    const int tid  = threadIdx.x;
    const int wave = tid >> 6;               // 0..3: 16-node strip
    const int lane = tid & 63;
    const int q    = lane >> 4;              // quad 0..3
    const int n    = lane & 15;

    // ---- B fragments once per block: B[k][col], k=kb*32+q*8+j, col=t*16+n --
    // t<4 -> P cols (W1 rows 0..63); t>=4 -> Q cols (W1 rows 64..127).
    bf16x8 bfrag[8][2];
    #pragma unroll
    for (int t = 0; t < 8; ++t) {
        const float* wb = W1 + ((t >= 4) ? HF * HF : 0) + (t & 3) * 16 + n;
        #pragma unroll
        for (int kb = 0; kb < 2; ++kb) {
            #pragma unroll
            for (int j = 0; j < 8; ++j)
                bfrag[t][kb][j] = f2bf(wb[(kb * 32 + q * 8 + j) * HF]);
        }
    }
    const float bias_n  = b1[0 * 16 + n];
    const float bias_n1 = b1[1 * 16 + n];
    const float bias_n2 = b1[2 * 16 + n];
    const float bias_n3 = b1[3 * 16 + n];

    for (int it = 0; it < TPB; ++it) {
        const int tile = blockIdx.x * TPB + it;
        const int n0   = tile * 64;
        if (n0 >= n_nodes) break;            // block-uniform
        const int nrow = (n_nodes - n0 < 64) ? (n_nodes - n0) : 64;

        // ---- A fragments direct from global: A[m][k], m=wave*16+n ----
        bf16x8 a0, a1;
        {
            int row = n0 + wave * 16 + n;
            if (row >= n_nodes) row = n_nodes - 1;
            const float* hr = h + (size_t)row * HF + q * 8;
            const float4 u0 = *(const float4*)(hr);
            const float4 u1 = *(const float4*)(hr + 4);
            const float4 v0 = *(const float4*)(hr + 32);
            const float4 v1 = *(const float4*)(hr + 36);
            a0[0] = f2bf(u0.x); a0[1] = f2bf(u0.y); a0[2] = f2bf(u0.z); a0[3] = f2bf(u0.w);
            a0[4] = f2bf(u1.x); a0[5] = f2bf(u1.y); a0[6] = f2bf(u1.z); a0[7] = f2bf(u1.w);
            a1[0] = f2bf(v0.x); a1[1] = f2bf(v0.y); a1[2] = f2bf(v0.z); a1[3] = f2bf(v0.w);
            a1[4] = f2bf(v1.x); a1[5] = f2bf(v1.y); a1[6] = f2bf(v1.z); a1[7] = f2bf(v1.w);
        }

        // ---- MFMA: 8 N-tiles x 2 K-halves ----
        f32x4 acc[8];
        #pragma unroll
        for (int t = 0; t < 8; ++t) {
            acc[t] = (f32x4){0.f, 0.f, 0.f, 0.f};
            acc[t] = __builtin_amdgcn_mfma_f32_16x16x32_bf16(a0, bfrag[t][0], acc[t], 0, 0, 0);
            acc[t] = __builtin_amdgcn_mfma_f32_16x16x32_bf16(a1, bfrag[t][1], acc[t], 0, 0, 0);
        }

        if (it > 0) __syncthreads();         // prev tile's eb8/pscl reads done

        // ---- epilogue: per-row amax -> int8 quant -> LDS ----
        // C/D layout: col = lane&15 (=n), row = q*4 + reg (+ wave*16).
        // A row's 64 cols live on the 16 lanes sharing q (t=0..3 regs each).
        #pragma unroll
        for (int r = 0; r < 4; ++r) {
            const int row = wave * 16 + q * 4 + r;
            const float p0 = acc[0][r] + bias_n;
            const float p1 = acc[1][r] + bias_n1;
            const float p2 = acc[2][r] + bias_n2;
            const float p3 = acc[3][r] + bias_n3;
            const float q0 = acc[4][r], q1 = acc[5][r];
            const float q2 = acc[6][r], q3 = acc[7][r];

            float pa = fmaxf(fmaxf(__builtin_fabsf(p0), __builtin_fabsf(p1)),
                             fmaxf(__builtin_fabsf(p2), __builtin_fabsf(p3)));
            float qa = fmaxf(fmaxf(__builtin_fabsf(q0), __builtin_fabsf(q1)),
                             fmaxf(__builtin_fabsf(q2), __builtin_fabsf(q3)));
            #pragma unroll
            for (int m = 1; m < 16; m <<= 1) {
                pa = fmaxf(pa, __shfl_xor(pa, m, 16));
                qa = fmaxf(qa, __shfl_xor(qa, m, 16));
            }
            pa = fmaxf(pa, 1e-12f);
            qa = fmaxf(qa, 1e-12f);
            const float pinv = 127.0f / pa;
            const float qinv = 127.0f / qa;

            unsigned char* er = eb8 + row * PITCH;
            er[ 0 + n]      = q8(p0, pinv);
            er[16 + n]      = q8(p1, pinv);
            er[32 + n]      = q8(p2, pinv);
            er[48 + n]      = q8(p3, pinv);
            er[64 +  0 + n] = q8(q0, qinv);
            er[64 + 16 + n] = q8(q1, qinv);
            er[64 + 32 + n] = q8(q2, qinv);
            er[64 + 48 + n] = q8(q3, qinv);
            if (n == 0) {
                pscl[row] = pa * (1.0f / 127.0f);
                qscl[row] = qa * (1.0f / 127.0f);
            }
        }
        __syncthreads();

        // ---- coalesced stores: one 128-B line [P|Q] per node row ----
        #pragma unroll
        for (int s = 0; s < 2; ++s) {
            const int idx  = tid + s * 256;   // 0..511 uint4s
            const int row  = idx >> 3;
            const int part = idx & 7;         // bytes [0,64)=P half, [64,128)=Q half
            if (row < nrow) {
                const uint4 v = *(const uint4*)&eb8[row * PITCH + part * 16];
                *(uint4*)(R + (size_t)(n0 + row) * RSTRIDE + part * 16) = v;
            }
        }
        if (tid < nrow) {
            *(float2*)(S + (size_t)(n0 + tid) * 2) =
                make_float2(pscl[tid], qscl[tid]);
        }
    }
}

// ---------------- Phase 2: per-edge score over interleaved int8 rows ------
__device__ __forceinline__ float dot8q(uint2 pv, uint2 qv, float4 wa, float4 wb,
                                       float ps, float qs) {
    const float C = -127.0f * (ps + qs);
    float acc = 0.f;
    {
        const unsigned u = pv.x, v = qv.x;
        float x;
        x = fmaf((float)(u & 255u),         ps, fmaf((float)(v & 255u),         qs, C));
        acc = fmaf(fmaxf(x, 0.f), wa.x, acc);
        x = fmaf((float)((u >> 8) & 255u),  ps, fmaf((float)((v >> 8) & 255u),  qs, C));
        acc = fmaf(fmaxf(x, 0.f), wa.y, acc);
        x = fmaf((float)((u >> 16) & 255u), ps, fmaf((float)((v >> 16) & 255u), qs, C));
        acc = fmaf(fmaxf(x, 0.f), wa.z, acc);
        x = fmaf((float)(u >> 24),          ps, fmaf((float)(v >> 24),          qs, C));
        acc = fmaf(fmaxf(x, 0.f), wa.w, acc);
    }
    {
        const unsigned u = pv.y, v = qv.y;
        float x;
        x = fmaf((float)(u & 255u),         ps, fmaf((float)(v & 255u),         qs, C));
        acc = fmaf(fmaxf(x, 0.f), wb.x, acc);
        x = fmaf((float)((u >> 8) & 255u),  ps, fmaf((float)((v >> 8) & 255u),  qs, C));
        acc = fmaf(fmaxf(x, 0.f), wb.y, acc);
        x = fmaf((float)((u >> 16) & 255u), ps, fmaf((float)((v >> 16) & 255u), qs, C));
        acc = fmaf(fmaxf(x, 0.f), wb.z, acc);
        x = fmaf((float)(u >> 24),          ps, fmaf((float)(v >> 24),          qs, C));
        acc = fmaf(fmaxf(x, 0.f), wb.w, acc);
    }
    return acc;
}

__device__ __forceinline__ float red8(float v) {
    v += __shfl_xor(v, 4, 8);
    v += __shfl_xor(v, 2, 8);
    v += __shfl_xor(v, 1, 8);
    return v;
}

__global__ __launch_bounds__(256) void edge_score_kernel(
    const unsigned char* __restrict__ R, const float* __restrict__ S,
    const int* __restrict__ src, const int* __restrict__ dst,
    const float* __restrict__ W2, const float* __restrict__ b2,
    float* __restrict__ out, int n_edges)
{
    const int tid   = blockIdx.x * 256 + threadIdx.x;
    const int sub   = threadIdx.x & 7;
    const int group = tid >> 3;
    const int j0    = sub * 8;
    const int e0    = group * 8;
    if (e0 >= n_edges) return;

    const float4 w2a = *(const float4*)(W2 + j0);
    const float4 w2b = *(const float4*)(W2 + j0 + 4);
    const float bias2 = b2[0];

    if (e0 + 8 <= n_edges) {
        const int4 sA = *(const int4*)(src + e0);
        const int4 sB = *(const int4*)(src + e0 + 4);
        const int4 dA = *(const int4*)(dst + e0);
        const int4 dB = *(const int4*)(dst + e0 + 4);

        // lane sub owns edge e0+sub: its scales gathered once, broadcast at use.
        // S is 0.8 MB -> L2-resident; interleaved (ps,qs) shares lines too.
        const float ps_own = S[2 * src[e0 + sub]];
        const float qs_own = S[2 * dst[e0 + sub] + 1];

        const uint2 p0 = *(const uint2*)(R + (size_t)sA.x * RSTRIDE + j0);
        const uint2 p1 = *(const uint2*)(R + (size_t)sA.y * RSTRIDE + j0);
        const uint2 p2 = *(const uint2*)(R + (size_t)sA.z * RSTRIDE + j0);
        const uint2 p3 = *(const uint2*)(R + (size_t)sA.w * RSTRIDE + j0);
        const uint2 p4 = *(const uint2*)(R + (size_t)sB.x * RSTRIDE + j0);
        const uint2 p5 = *(const uint2*)(R + (size_t)sB.y * RSTRIDE + j0);
        const uint2 p6 = *(const uint2*)(R + (size_t)sB.z * RSTRIDE + j0);
        const uint2 p7 = *(const uint2*)(R + (size_t)sB.w * RSTRIDE + j0);
        const uint2 q0 = *(const uint2*)(R + (size_t)dA.x * RSTRIDE + 64 + j0);
        const uint2 q1 = *(const uint2*)(R + (size_t)dA.y * RSTRIDE + 64 + j0);
        const uint2 q2 = *(const uint2*)(R + (size_t)dA.z * RSTRIDE + 64 + j0);
        const uint2 q3 = *(const uint2*)(R + (size_t)dA.w * RSTRIDE + 64 + j0);
        const uint2 q4 = *(const uint2*)(R + (size_t)dB.x * RSTRIDE + 64 + j0);
        const uint2 q5 = *(const uint2*)(R + (size_t)dB.y * RSTRIDE + 64 + j0);
        const uint2 q6 = *(const uint2*)(R + (size_t)dB.z * RSTRIDE + 64 + j0);
        const uint2 q7 = *(const uint2*)(R + (size_t)dB.w * RSTRIDE + 64 + j0);

        float s0 = red8(dot8q(p0, q0, w2a, w2b, __shfl(ps_own, 0, 8), __shfl(qs_own, 0, 8)));
        float s1 = red8(dot8q(p1, q1, w2a, w2b, __shfl(ps_own, 1, 8), __shfl(qs_own, 1, 8)));
        float s2 = red8(dot8q(p2, q2, w2a, w2b, __shfl(ps_own, 2, 8), __shfl(qs_own, 2, 8)));
        float s3 = red8(dot8q(p3, q3, w2a, w2b, __shfl(ps_own, 3, 8), __shfl(qs_own, 3, 8)));
        float s4 = red8(dot8q(p4, q4, w2a, w2b, __shfl(ps_own, 4, 8), __shfl(qs_own, 4, 8)));
        float s5 = red8(dot8q(p5, q5, w2a, w2b, __shfl(ps_own, 5, 8), __shfl(qs_own, 5, 8)));
        float s6 = red8(dot8q(p6, q6, w2a, w2b, __shfl(ps_own, 6, 8), __shfl(qs_own, 6, 8)));
        float s7 = red8(dot8q(p7, q7, w2a, w2b, __shfl(ps_own, 7, 8), __shfl(qs_own, 7, 8)));

        if (sub == 0) {
            *(float4*)(out + e0)     = make_float4(s0 + bias2, s1 + bias2,
                                                   s2 + bias2, s3 + bias2);
            *(float4*)(out + e0 + 4) = make_float4(s4 + bias2, s5 + bias2,
                                                   s6 + bias2, s7 + bias2);
        }
    } else {
        for (int e = e0; e < n_edges; ++e) {
            const int s = src[e];
            const int d = dst[e];
            const float ps = S[2 * s];
            const float qs = S[2 * d + 1];
            const uint2 pv = *(const uint2*)(R + (size_t)s * RSTRIDE + j0);
            const uint2 qv = *(const uint2*)(R + (size_t)d * RSTRIDE + 64 + j0);
            float sc = red8(dot8q(pv, qv, w2a, w2b, ps, qs));
            if (sub == 0) out[e] = sc + bias2;
        }
    }
}

extern "C" void kernel_launch(void* const* d_in, const int* in_sizes, int n_in,
                              void* d_out, int out_size, void* d_ws, size_t ws_size,
                              hipStream_t stream) {
    const float* h   = (const float*)d_in[0];
    const int*   src = (const int*)d_in[1];
    const int*   dst = (const int*)d_in[2];
    const float* W1  = (const float*)d_in[3];
    const float* b1  = (const float*)d_in[4];
    const float* W2  = (const float*)d_in[5];
    const float* b2  = (const float*)d_in[6];
    float* out = (float*)d_out;

    const int n_nodes = in_sizes[0] / HF;
    const int n_edges = in_sizes[1];

    unsigned char* R = (unsigned char*)d_ws;                    // 12.8 MB
    float* S = (float*)(R + (size_t)n_nodes * RSTRIDE);         // 0.8 MB

    const int ntiles   = (n_nodes + 63) / 64;
    const int nblocks1 = (ntiles + TPB - 1) / TPB;       // 2 tiles per block
    node_proj_kernel<<<nblocks1, 256, 0, stream>>>(h, W1, b1, R, S, n_nodes);

    const int ngroups  = (n_edges + 7) / 8;              // 8 edges per 8-lane group
    const int nblocks2 = (ngroups + 31) / 32;            // 32 groups per 256-thr block
    edge_score_kernel<<<nblocks2, 256, 0, stream>>>(R, S, src, dst, W2, b2, out, n_edges);
}